// Round 11
// baseline (316.458 us; speedup 1.0000x reference)
//
#include <hip/hip_runtime.h>
#include <stdint.h>

typedef unsigned short u16;
typedef short s16x8 __attribute__((ext_vector_type(8)));
typedef float f32x4 __attribute__((ext_vector_type(4)));

#define DIM 384
#define HID 1536
#define NSEQ 2048
#define SCALE 0.14433756729740643f

__device__ __forceinline__ u16 f2b(float f) {
  union { float f; unsigned int u; } x; x.f = f;
  unsigned int u = x.u + 0x7FFFu + ((x.u >> 16) & 1u);
  return (u16)(u >> 16);
}

__device__ __forceinline__ f32x4 mfma16(s16x8 a, s16x8 b, f32x4 c) {
  return __builtin_amdgcn_mfma_f32_16x16x32_bf16(a, b, c, 0, 0, 0);
}

#define GLOBAL_AS __attribute__((address_space(1)))
#define LDS_AS __attribute__((address_space(3)))
__device__ __forceinline__ void gload_lds16(const void* g, void* l) {
  __builtin_amdgcn_global_load_lds((const GLOBAL_AS unsigned int*)g,
                                   (LDS_AS unsigned int*)l, 16, 0, 0);
}

// ---------------- zero + convert (merged) ----------------
__global__ void convert_zero(const float* __restrict__ wq, const float* __restrict__ wk,
                             const float* __restrict__ wv, const float* __restrict__ wo,
                             const float* __restrict__ wfc1, const float* __restrict__ wfc2,
                             u16* __restrict__ wqkv_b, u16* __restrict__ wo_b,
                             u16* __restrict__ wfc1_b, u16* __restrict__ wfc2_b,
                             uint4* __restrict__ zp) {
  for (int i = blockIdx.x * blockDim.x + threadIdx.x; i < 1572864; i += gridDim.x * blockDim.x)
    zp[i] = make_uint4(0u, 0u, 0u, 0u);
  const int total = 442368 + 147456 + 589824 + 589824;
  for (int i = blockIdx.x * blockDim.x + threadIdx.x; i < total; i += gridDim.x * blockDim.x) {
    int j = i;
    if (j < 442368) {
      const int row = j / 384, k = j - row * 384;
      float v;
      if (row < 384) v = wq[row * 384 + k] * SCALE;
      else if (row < 768) v = wk[(row - 384) * 384 + k];
      else v = wv[(row - 768) * 384 + k];
      wqkv_b[j] = f2b(v);
    } else if ((j -= 442368) < 147456) {
      wo_b[j] = f2b(wo[j]);
    } else if ((j -= 147456) < 589824) {
      wfc1_b[j] = f2b(wfc1[j]);
    } else {
      j -= 589824;
      wfc2_b[j] = f2b(wfc2[j]);
    }
  }
}

// ---------------- layernorm (1 wave per 384-row) ----------------
__global__ __launch_bounds__(256) void ln_kernel(
    const float* __restrict__ in, const float* __restrict__ g, const float* __restrict__ b,
    float* outf, u16* outb) {
  const int w = threadIdx.x >> 6, l = threadIdx.x & 63;
  const size_t row = (size_t)blockIdx.x * 4 + w;
  const float* r = in + row * DIM;
  float v[6];
  #pragma unroll
  for (int i = 0; i < 6; ++i) v[i] = r[l + 64 * i];
  float s = 0.f;
  #pragma unroll
  for (int i = 0; i < 6; ++i) s += v[i];
  #pragma unroll
  for (int m = 1; m < 64; m <<= 1) s += __shfl_xor(s, m);
  const float mu = s * (1.0f / 384.0f);
  float q = 0.f;
  #pragma unroll
  for (int i = 0; i < 6; ++i) { const float d = v[i] - mu; q += d * d; }
  #pragma unroll
  for (int m = 1; m < 64; m <<= 1) q += __shfl_xor(q, m);
  const float rs = rsqrtf(q * (1.0f / 384.0f) + 1e-5f);
  #pragma unroll
  for (int i = 0; i < 6; ++i) {
    const int c = l + 64 * i;
    const float o = (v[i] - mu) * rs * g[c] + b[c];
    if (outf) outf[row * DIM + c] = o;
    outb[row * DIM + c] = f2b(o);
  }
}

// ---------------- 128x128 NT bf16 GEMM (EPI 0=QKV scatter, 2=fc1 gelu) ----------------
template<int EPI>
__global__ __launch_bounds__(256, 2) void gemm_nt(
    const u16* __restrict__ A, const u16* __restrict__ B, int K,
    const float* bias, const float* resid, float* outf, u16* outb) {
  __shared__ u16 As[4096];
  __shared__ u16 Bs[4096];
  const int tid = threadIdx.x;
  const int w = tid >> 6, l = tid & 63;
  const int lr = l & 15, lg = l >> 4;
  const int Mt = blockIdx.x << 7, Nt = blockIdx.y << 7;
  const int wr = (w >> 1) << 6, wc = (w & 1) << 6;

  f32x4 acc[4][4];
  const f32x4 zf = {0.f, 0.f, 0.f, 0.f};
  #pragma unroll
  for (int i = 0; i < 4; ++i)
    #pragma unroll
    for (int j = 0; j < 4; ++j) acc[i][j] = zf;

  const int srow = l >> 2;
  const int scol = (l & 3) << 3;
  const int nk = K >> 5;
  for (int kt = 0; kt < nk; ++kt) {
    const int k0 = kt << 5;
    __syncthreads();
    #pragma unroll
    for (int i = 0; i < 2; ++i) {
      const int chunk = i * 4 + w;
      const int row = chunk * 16 + srow;
      gload_lds16(A + (size_t)(Mt + row) * K + k0 + scol, As + chunk * 512);
      gload_lds16(B + (size_t)(Nt + row) * K + k0 + scol, Bs + chunk * 512);
    }
    asm volatile("s_waitcnt vmcnt(0)" ::: "memory");
    __syncthreads();
    s16x8 fa[4], fb[4];
    #pragma unroll
    for (int i = 0; i < 4; ++i) {
      fa[i] = *(const s16x8*)(As + (wr + i * 16 + lr) * 32 + lg * 8);
      fb[i] = *(const s16x8*)(Bs + (wc + i * 16 + lr) * 32 + lg * 8);
    }
    #pragma unroll
    for (int i = 0; i < 4; ++i)
      #pragma unroll
      for (int j = 0; j < 4; ++j)
        acc[i][j] = mfma16(fa[i], fb[j], acc[i][j]);
  }

  #pragma unroll
  for (int i = 0; i < 4; ++i) {
    #pragma unroll
    for (int j = 0; j < 4; ++j) {
      #pragma unroll
      for (int r = 0; r < 4; ++r) {
        const int m = Mt + wr + i * 16 + lg * 4 + r;
        const int n = Nt + wc + j * 16 + lr;
        const float v = acc[i][j][r];
        if (EPI == 0) {
          const int b_ = m >> 11, t = m & 2047;
          int proj, c;
          if (n < 384) { proj = 0; c = n; }
          else if (n < 768) { proj = 1; c = n - 384; }
          else { proj = 2; c = n - 768; }
          const int head = c / 48;
          const int d = c - head * 48;
          const size_t bh = (size_t)(b_ * 8 + head);
          const u16 bv = f2b(v);
          if (proj == 0)      outb[(bh * 2048 + t) * 64 + d] = bv;            // q [bh][t][64]
          else if (proj == 1) outb[4194304 + (bh * 2048 + t) * 64 + d] = bv;  // k [bh][t][64]
          else                outb[8388608 + (bh * 64 + d) * 2048 + t] = bv;  // vT [bh][64][t]
        } else {
          const float u = v + bias[n];
          const float ge = 0.5f * u * (1.0f + erff(u * 0.70710678118654752f));
          outb[(size_t)m * HID + n] = f2b(ge);
        }
      }
    }
  }
}

// ---------------- 128x64 NT bf16 GEMM (+resid+bias) for N=384 GEMMs ----------------
__global__ __launch_bounds__(256, 2) void gemm_n64(
    const u16* __restrict__ A, const u16* __restrict__ B, int K,
    const float* bias, const float* resid, float* outf) {
  __shared__ u16 As[4096];  // 128 x 32
  __shared__ u16 Bs[2048];  // 64 x 32
  const int tid = threadIdx.x;
  const int w = tid >> 6, l = tid & 63;
  const int lr = l & 15, lg = l >> 4;
  const int Mt = blockIdx.x << 7, Nt = blockIdx.y << 6;
  const int wr = (w >> 1) << 6, wc = (w & 1) << 5;

  f32x4 acc[4][2];
  const f32x4 zf = {0.f, 0.f, 0.f, 0.f};
  #pragma unroll
  for (int i = 0; i < 4; ++i)
    #pragma unroll
    for (int j = 0; j < 2; ++j) acc[i][j] = zf;

  const int srow = l >> 2;
  const int scol = (l & 3) << 3;
  const int nk = K >> 5;
  for (int kt = 0; kt < nk; ++kt) {
    const int k0 = kt << 5;
    __syncthreads();
    #pragma unroll
    for (int i = 0; i < 2; ++i) {
      const int chunk = i * 4 + w;
      gload_lds16(A + (size_t)(Mt + chunk * 16 + srow) * K + k0 + scol, As + chunk * 512);
    }
    gload_lds16(B + (size_t)(Nt + w * 16 + srow) * K + k0 + scol, Bs + w * 512);
    asm volatile("s_waitcnt vmcnt(0)" ::: "memory");
    __syncthreads();
    s16x8 fa[4], fb[2];
    #pragma unroll
    for (int i = 0; i < 4; ++i)
      fa[i] = *(const s16x8*)(As + (wr + i * 16 + lr) * 32 + lg * 8);
    #pragma unroll
    for (int j = 0; j < 2; ++j)
      fb[j] = *(const s16x8*)(Bs + (wc + j * 16 + lr) * 32 + lg * 8);
    #pragma unroll
    for (int i = 0; i < 4; ++i)
      #pragma unroll
      for (int j = 0; j < 2; ++j)
        acc[i][j] = mfma16(fa[i], fb[j], acc[i][j]);
  }

  #pragma unroll
  for (int i = 0; i < 4; ++i) {
    #pragma unroll
    for (int j = 0; j < 2; ++j) {
      #pragma unroll
      for (int r = 0; r < 4; ++r) {
        const int m = Mt + wr + i * 16 + lg * 4 + r;
        const int n = Nt + wc + j * 16 + lr;
        const size_t idx = (size_t)m * DIM + n;
        outf[idx] = resid[idx] + acc[i][j][r] + bias[n];
      }
    }
  }
}

// ---------------- Kernel A: flash attention, 32 q-rows/wave, shared K/V LDS staging --
__global__ __launch_bounds__(256, 2) void attn_flash(
    const u16* __restrict__ qg, const u16* __restrict__ kg, const u16* __restrict__ vtg,
    float* __restrict__ rinv_out, u16* __restrict__ obf) {
  __shared__ char Ks[2][9216];   // [buf][64 rows x 144B]
  __shared__ char Vs[2][9216];
  __shared__ u16 Pl[4][2048];    // per-wave 4KB P chunk
  const int bid0 = blockIdx.x;
  const int bid = (bid0 & 7) * 64 + (bid0 >> 3);   // XCD-chunked (512 % 8 == 0)
  const int tid = threadIdx.x;
  const int w = tid >> 6, l = tid & 63;
  const int lr = l & 15, lg = l >> 4;
  const int task = bid * 4 + w;     // 64 tasks per bh; all 4 waves same bh
  const int bh = task >> 6;
  const int q0 = (task & 63) << 5;
  const u16* qh = qg + (size_t)bh * 131072;
  const char* kgb = (const char*)(kg + (size_t)bh * 131072);
  const char* vgb = (const char*)(vtg + (size_t)bh * 131072);
  char* myP = (char*)&Pl[w][0];
  const int swz = (lr & 7) << 4;

  const int o0 = tid * 16, o1 = tid * 16 + 4096;
  const int r0 = o0 >> 7, c0 = o0 & 127;
  const int r1 = o1 >> 7, c1 = o1 & 127;

  s16x8 bq[2][2];
  #pragma unroll
  for (int g = 0; g < 2; ++g)
    #pragma unroll
    for (int dh = 0; dh < 2; ++dh)
      bq[g][dh] = *(const s16x8*)(qh + (size_t)(q0 + g * 16 + lr) * 64 + dh * 32 + lg * 8);

  const f32x4 zf = {0.f, 0.f, 0.f, 0.f};
  f32x4 oacc[2][3];
  #pragma unroll
  for (int g = 0; g < 2; ++g)
    #pragma unroll
    for (int d = 0; d < 3; ++d) oacc[g][d] = zf;
  float suml[2] = {0.f, 0.f};

  {
    uint4 k0v = *(const uint4*)(kgb + o0);
    uint4 k1v = *(const uint4*)(kgb + o1);
    uint4 v0v = *(const uint4*)(vgb + (size_t)r0 * 4096 + c0);
    uint4 v1v = *(const uint4*)(vgb + (size_t)r1 * 4096 + c1);
    *(uint4*)(Ks[0] + r0 * 144 + c0) = k0v;
    *(uint4*)(Ks[0] + r1 * 144 + c1) = k1v;
    *(uint4*)(Vs[0] + r0 * 144 + c0) = v0v;
    *(uint4*)(Vs[0] + r1 * 144 + c1) = v1v;
  }

  #pragma unroll 2
  for (int cc = 0; cc < 32; ++cc) {
    const int cur = cc & 1;
    uint4 k0v, k1v, v0v, v1v;
    if (cc < 31) {
      const int cc1 = cc + 1;
      k0v = *(const uint4*)(kgb + cc1 * 8192 + o0);
      k1v = *(const uint4*)(kgb + cc1 * 8192 + o1);
      v0v = *(const uint4*)(vgb + (size_t)r0 * 4096 + cc1 * 128 + c0);
      v1v = *(const uint4*)(vgb + (size_t)r1 * 4096 + cc1 * 128 + c1);
    }
    __syncthreads();

    #pragma unroll
    for (int t = 0; t < 4; ++t) {
      const char* krp = Ks[cur] + (t * 16 + lr) * 144 + lg * 16;
      const s16x8 ak0 = *(const s16x8*)krp;
      const s16x8 ak1 = *(const s16x8*)(krp + 64);
      #pragma unroll
      for (int g = 0; g < 2; ++g) {
        f32x4 c = mfma16(ak0, bq[g][0], zf);
        c = mfma16(ak1, bq[g][1], c);
        f32x4 e;
        #pragma unroll
        for (int r = 0; r < 4; ++r) e[r] = __expf(c[r]);
        suml[g] += (e[0] + e[1]) + (e[2] + e[3]);
        const int q = g * 16 + lr;
        const unsigned int lo = (unsigned int)f2b(e[0]) | ((unsigned int)f2b(e[1]) << 16);
        const unsigned int hi = (unsigned int)f2b(e[2]) | ((unsigned int)f2b(e[3]) << 16);
        *(uint2*)(myP + ((q * 128 + t * 32 + lg * 8) ^ swz)) = make_uint2(lo, hi);
      }
    }
    s16x8 pa[2][2];
    #pragma unroll
    for (int g = 0; g < 2; ++g) {
      const int q = g * 16 + lr;
      #pragma unroll
      for (int ks = 0; ks < 2; ++ks)
        pa[g][ks] = *(const s16x8*)(myP + ((q * 128 + ks * 64 + lg * 16) ^ swz));
    }
    #pragma unroll
    for (int ks = 0; ks < 2; ++ks) {
      #pragma unroll
      for (int d = 0; d < 3; ++d) {
        const s16x8 vb = *(const s16x8*)(Vs[cur] + (d * 16 + lr) * 144 + ks * 64 + lg * 16);
        #pragma unroll
        for (int g = 0; g < 2; ++g)
          oacc[g][d] = mfma16(pa[g][ks], vb, oacc[g][d]);
      }
    }
    if (cc < 31) {
      *(uint4*)(Ks[cur ^ 1] + r0 * 144 + c0) = k0v;
      *(uint4*)(Ks[cur ^ 1] + r1 * 144 + c1) = k1v;
      *(uint4*)(Vs[cur ^ 1] + r0 * 144 + c0) = v0v;
      *(uint4*)(Vs[cur ^ 1] + r1 * 144 + c1) = v1v;
    }
  }

  float rinv[2];
  #pragma unroll
  for (int g = 0; g < 2; ++g) {
    float s = suml[g];
    s += __shfl_xor(s, 16);
    s += __shfl_xor(s, 32);
    rinv[g] = 1.0f / s;
  }
  if (l < 16) {
    rinv_out[bh * 2048 + q0 + l] = rinv[0];
    rinv_out[bh * 2048 + q0 + 16 + l] = rinv[1];
  }
  const int b_ = bh >> 3, h = bh & 7;
  #pragma unroll
  for (int g = 0; g < 2; ++g) {
    #pragma unroll
    for (int r = 0; r < 4; ++r) {
      const float sc = __shfl(rinv[g], lg * 4 + r);
      const int qrow = q0 + g * 16 + lg * 4 + r;
      #pragma unroll
      for (int d = 0; d < 3; ++d) {
        obf[((size_t)b_ * 2048 + qrow) * DIM + h * 48 + d * 16 + lr] = f2b(oacc[g][d][r] * sc);
      }
    }
  }
}

// ---------------- Kernel B: P writer v6 — block-cooperative, 4KB-contiguous row stores --
// 8192 blocks x 4 waves; block = (bh, 16-q tile, 1024-key half).
// Wave w computes keys [w*256,(w+1)*256) for all 16 q -> block LDS [16][1028].
// One barrier, then 16 rows stored in ascending address order, each row one
// 4KB lane-contiguous NT blast (256 threads x f32x4).
__global__ __launch_bounds__(256, 2) void p_writer(
    const u16* __restrict__ qg, const u16* __restrict__ kg,
    const float* __restrict__ rinv_g, float* __restrict__ pout) {
  __shared__ float Pt[16][1028];   // 65,792 B -> 2 blocks/CU; stride%32==4 -> 2-way (free)
  const int bid0 = blockIdx.x;
  const int bid = (bid0 & 7) * 1024 + (bid0 >> 3);  // 8192 % 8 == 0, bijective
  const int tid = threadIdx.x;
  const int w = tid >> 6, l = tid & 63;
  const int lr = l & 15, lg = l >> 4;
  const int bh = bid >> 8;                 // 256 blocks per bh
  const int t = bid & 255;
  const int qt = t >> 1, hf = t & 1;
  const int q0 = qt << 4;
  const int kbase = hf << 10;              // 0 or 1024
  const int k0 = kbase + (w << 8);         // wave's 256-key range
  const u16* qh = qg + (size_t)bh * 131072;
  const u16* kp = kg + (size_t)bh * 131072;

  const s16x8 bq0 = *(const s16x8*)(qh + (size_t)(q0 + lr) * 64 + lg * 8);
  const s16x8 bq1 = *(const s16x8*)(qh + (size_t)(q0 + lr) * 64 + 32 + lg * 8);
  const float rinv = rinv_g[bh * 2048 + q0 + lr];
  const f32x4 zf = {0.f, 0.f, 0.f, 0.f};

  #pragma unroll 4
  for (int kk = 0; kk < 16; ++kk) {
    const u16* kr = kp + (size_t)(k0 + kk * 16 + lr) * 64 + lg * 8;
    const s16x8 ak0 = *(const s16x8*)kr;
    const s16x8 ak1 = *(const s16x8*)(kr + 32);
    f32x4 c = mfma16(ak0, bq0, zf);
    c = mfma16(ak1, bq1, c);
    f32x4 e;
    #pragma unroll
    for (int r = 0; r < 4; ++r) e[r] = __expf(c[r]) * rinv;
    *(f32x4*)&Pt[lr][(w << 8) + kk * 16 + lg * 4] = e;   // q=lr, local key col
  }
  __syncthreads();
  // store phase: rows in ascending address order, 4KB contiguous per row
  float* pbase = pout + (size_t)bh * 4194304 + (size_t)q0 * 2048 + kbase;
  const int col = tid * 4;   // 0..1020
  #pragma unroll
  for (int r = 0; r < 16; ++r) {
    const f32x4 vq = *(const f32x4*)&Pt[r][col];
    __builtin_nontemporal_store(vq, (f32x4*)(pbase + (size_t)r * 2048 + col));
  }
}

// ---------------- launch ----------------
extern "C" void kernel_launch(void* const* d_in, const int* in_sizes, int n_in,
                              void* d_out, int out_size, void* d_ws, size_t ws_size,
                              hipStream_t stream) {
  const float* x    = (const float*)d_in[0];
  const float* wq   = (const float*)d_in[1];
  const float* wk   = (const float*)d_in[2];
  const float* wv   = (const float*)d_in[3];
  const float* wo   = (const float*)d_in[4];
  const float* bo   = (const float*)d_in[5];
  const float* g1   = (const float*)d_in[6];
  const float* b1   = (const float*)d_in[7];
  const float* g2   = (const float*)d_in[8];
  const float* b2   = (const float*)d_in[9];
  const float* wfc1 = (const float*)d_in[10];
  const float* bfc1 = (const float*)d_in[11];
  const float* wfc2 = (const float*)d_in[12];
  const float* bfc2 = (const float*)d_in[13];

  char* ws = (char*)d_ws;
  float* h_y    = (float*)(ws);                 // 12,582,912 B (h, later y in-place)
  u16*  h_bf    = (u16*)(ws + 12582912);        // 6,291,456  (later z_bf)
  u16*  wqkv_b  = (u16*)(ws + 18874368);        // 884,736
  u16*  wo_b    = (u16*)(ws + 19759104);        // 294,912
  u16*  wfc1_b  = (u16*)(ws + 20054016);        // 1,179,648
  u16*  wfc2_b  = (u16*)(ws + 21233664);        // 1,179,648
  u16*  qkv     = (u16*)(ws + 22413312);        // 25,165,824 (q|k|vT, later a_bf)
  u16*  o_bf    = (u16*)(ws + 47579136);        // 6,291,456
  float* rinv_g = (float*)(ws + 53870592);      // 262,144 -> total 54,132,736
  u16*  z_bf    = h_bf;
  u16*  a_bf    = qkv;

  float* y_out    = (float*)d_out;
  float* attn_out = (float*)d_out + 3145728;

  convert_zero<<<2048, 256, 0, stream>>>(wq, wk, wv, wo, wfc1, wfc2,
                                         wqkv_b, wo_b, wfc1_b, wfc2_b, (uint4*)qkv);
  ln_kernel<<<2048, 256, 0, stream>>>(x, g1, b1, h_y, h_bf);
  gemm_nt<0><<<dim3(64, 9), 256, 0, stream>>>(h_bf, wqkv_b, 384, nullptr, nullptr, nullptr, qkv);
  attn_flash<<<512, 256, 0, stream>>>(qkv, qkv + 4194304, qkv + 8388608, rinv_g, o_bf);
  p_writer<<<8192, 256, 0, stream>>>(qkv, qkv + 4194304, rinv_g, attn_out);
  gemm_n64<<<dim3(64, 6), 256, 0, stream>>>(o_bf, wo_b, 384, bo, h_y, h_y);
  ln_kernel<<<2048, 256, 0, stream>>>(h_y, g2, b2, nullptr, z_bf);
  gemm_nt<2><<<dim3(64, 12), 256, 0, stream>>>(z_bf, wfc1_b, 384, bfc1, nullptr, nullptr, a_bf);
  gemm_n64<<<dim3(64, 6), 256, 0, stream>>>(a_bf, wfc2_b, 1536, bfc2, h_y, y_out);
}

// Round 12
// 209.336 us; speedup vs baseline: 1.5117x; 1.5117x over previous
//
#include <hip/hip_runtime.h>
#include <stdint.h>

typedef unsigned short u16;
typedef short s16x8 __attribute__((ext_vector_type(8)));
typedef float f32x4 __attribute__((ext_vector_type(4)));

#define DIM 384
#define HID 1536
#define NSEQ 2048
#define SCALE 0.14433756729740643f

__device__ __forceinline__ u16 f2b(float f) {
  union { float f; unsigned int u; } x; x.f = f;
  unsigned int u = x.u + 0x7FFFu + ((x.u >> 16) & 1u);
  return (u16)(u >> 16);
}

__device__ __forceinline__ f32x4 mfma16(s16x8 a, s16x8 b, f32x4 c) {
  return __builtin_amdgcn_mfma_f32_16x16x32_bf16(a, b, c, 0, 0, 0);
}

#define GLOBAL_AS __attribute__((address_space(1)))
#define LDS_AS __attribute__((address_space(3)))
__device__ __forceinline__ void gload_lds16(const void* g, void* l) {
  __builtin_amdgcn_global_load_lds((const GLOBAL_AS unsigned int*)g,
                                   (LDS_AS unsigned int*)l, 16, 0, 0);
}

// ---------------- zero + convert (merged) ----------------
__global__ void convert_zero(const float* __restrict__ wq, const float* __restrict__ wk,
                             const float* __restrict__ wv, const float* __restrict__ wo,
                             const float* __restrict__ wfc1, const float* __restrict__ wfc2,
                             u16* __restrict__ wqkv_b, u16* __restrict__ wo_b,
                             u16* __restrict__ wfc1_b, u16* __restrict__ wfc2_b,
                             uint4* __restrict__ zp) {
  for (int i = blockIdx.x * blockDim.x + threadIdx.x; i < 1572864; i += gridDim.x * blockDim.x)
    zp[i] = make_uint4(0u, 0u, 0u, 0u);
  const int total = 442368 + 147456 + 589824 + 589824;
  for (int i = blockIdx.x * blockDim.x + threadIdx.x; i < total; i += gridDim.x * blockDim.x) {
    int j = i;
    if (j < 442368) {
      const int row = j / 384, k = j - row * 384;
      float v;
      if (row < 384) v = wq[row * 384 + k] * SCALE;
      else if (row < 768) v = wk[(row - 384) * 384 + k];
      else v = wv[(row - 768) * 384 + k];
      wqkv_b[j] = f2b(v);
    } else if ((j -= 442368) < 147456) {
      wo_b[j] = f2b(wo[j]);
    } else if ((j -= 147456) < 589824) {
      wfc1_b[j] = f2b(wfc1[j]);
    } else {
      j -= 589824;
      wfc2_b[j] = f2b(wfc2[j]);
    }
  }
}

// ---------------- layernorm (1 wave per 384-row) ----------------
__global__ __launch_bounds__(256) void ln_kernel(
    const float* __restrict__ in, const float* __restrict__ g, const float* __restrict__ b,
    float* outf, u16* outb) {
  const int w = threadIdx.x >> 6, l = threadIdx.x & 63;
  const size_t row = (size_t)blockIdx.x * 4 + w;
  const float* r = in + row * DIM;
  float v[6];
  #pragma unroll
  for (int i = 0; i < 6; ++i) v[i] = r[l + 64 * i];
  float s = 0.f;
  #pragma unroll
  for (int i = 0; i < 6; ++i) s += v[i];
  #pragma unroll
  for (int m = 1; m < 64; m <<= 1) s += __shfl_xor(s, m);
  const float mu = s * (1.0f / 384.0f);
  float q = 0.f;
  #pragma unroll
  for (int i = 0; i < 6; ++i) { const float d = v[i] - mu; q += d * d; }
  #pragma unroll
  for (int m = 1; m < 64; m <<= 1) q += __shfl_xor(q, m);
  const float rs = rsqrtf(q * (1.0f / 384.0f) + 1e-5f);
  #pragma unroll
  for (int i = 0; i < 6; ++i) {
    const int c = l + 64 * i;
    const float o = (v[i] - mu) * rs * g[c] + b[c];
    if (outf) outf[row * DIM + c] = o;
    outb[row * DIM + c] = f2b(o);
  }
}

// ---------------- 128x128 NT bf16 GEMM (EPI 0=QKV scatter, 2=fc1 gelu) ----------------
template<int EPI>
__global__ __launch_bounds__(256, 2) void gemm_nt(
    const u16* __restrict__ A, const u16* __restrict__ B, int K,
    const float* bias, const float* resid, float* outf, u16* outb) {
  __shared__ u16 As[4096];
  __shared__ u16 Bs[4096];
  const int tid = threadIdx.x;
  const int w = tid >> 6, l = tid & 63;
  const int lr = l & 15, lg = l >> 4;
  const int Mt = blockIdx.x << 7, Nt = blockIdx.y << 7;
  const int wr = (w >> 1) << 6, wc = (w & 1) << 6;

  f32x4 acc[4][4];
  const f32x4 zf = {0.f, 0.f, 0.f, 0.f};
  #pragma unroll
  for (int i = 0; i < 4; ++i)
    #pragma unroll
    for (int j = 0; j < 4; ++j) acc[i][j] = zf;

  const int srow = l >> 2;
  const int scol = (l & 3) << 3;
  const int nk = K >> 5;
  for (int kt = 0; kt < nk; ++kt) {
    const int k0 = kt << 5;
    __syncthreads();
    #pragma unroll
    for (int i = 0; i < 2; ++i) {
      const int chunk = i * 4 + w;
      const int row = chunk * 16 + srow;
      gload_lds16(A + (size_t)(Mt + row) * K + k0 + scol, As + chunk * 512);
      gload_lds16(B + (size_t)(Nt + row) * K + k0 + scol, Bs + chunk * 512);
    }
    asm volatile("s_waitcnt vmcnt(0)" ::: "memory");
    __syncthreads();
    s16x8 fa[4], fb[4];
    #pragma unroll
    for (int i = 0; i < 4; ++i) {
      fa[i] = *(const s16x8*)(As + (wr + i * 16 + lr) * 32 + lg * 8);
      fb[i] = *(const s16x8*)(Bs + (wc + i * 16 + lr) * 32 + lg * 8);
    }
    #pragma unroll
    for (int i = 0; i < 4; ++i)
      #pragma unroll
      for (int j = 0; j < 4; ++j)
        acc[i][j] = mfma16(fa[i], fb[j], acc[i][j]);
  }

  #pragma unroll
  for (int i = 0; i < 4; ++i) {
    #pragma unroll
    for (int j = 0; j < 4; ++j) {
      #pragma unroll
      for (int r = 0; r < 4; ++r) {
        const int m = Mt + wr + i * 16 + lg * 4 + r;
        const int n = Nt + wc + j * 16 + lr;
        const float v = acc[i][j][r];
        if (EPI == 0) {
          const int b_ = m >> 11, t = m & 2047;
          int proj, c;
          if (n < 384) { proj = 0; c = n; }
          else if (n < 768) { proj = 1; c = n - 384; }
          else { proj = 2; c = n - 768; }
          const int head = c / 48;
          const int d = c - head * 48;
          const size_t bh = (size_t)(b_ * 8 + head);
          const u16 bv = f2b(v);
          if (proj == 0)      outb[(bh * 2048 + t) * 64 + d] = bv;            // q [bh][t][64]
          else if (proj == 1) outb[4194304 + (bh * 2048 + t) * 64 + d] = bv;  // k [bh][t][64]
          else                outb[8388608 + (bh * 64 + d) * 2048 + t] = bv;  // vT [bh][64][t]
        } else {
          const float u = v + bias[n];
          const float ge = 0.5f * u * (1.0f + erff(u * 0.70710678118654752f));
          outb[(size_t)m * HID + n] = f2b(ge);
        }
      }
    }
  }
}

// ---------------- 128x64 NT bf16 GEMM (+resid+bias) for N=384 GEMMs ----------------
__global__ __launch_bounds__(256, 2) void gemm_n64(
    const u16* __restrict__ A, const u16* __restrict__ B, int K,
    const float* bias, const float* resid, float* outf) {
  __shared__ u16 As[4096];  // 128 x 32
  __shared__ u16 Bs[2048];  // 64 x 32
  const int tid = threadIdx.x;
  const int w = tid >> 6, l = tid & 63;
  const int lr = l & 15, lg = l >> 4;
  const int Mt = blockIdx.x << 7, Nt = blockIdx.y << 6;
  const int wr = (w >> 1) << 6, wc = (w & 1) << 5;

  f32x4 acc[4][2];
  const f32x4 zf = {0.f, 0.f, 0.f, 0.f};
  #pragma unroll
  for (int i = 0; i < 4; ++i)
    #pragma unroll
    for (int j = 0; j < 2; ++j) acc[i][j] = zf;

  const int srow = l >> 2;
  const int scol = (l & 3) << 3;
  const int nk = K >> 5;
  for (int kt = 0; kt < nk; ++kt) {
    const int k0 = kt << 5;
    __syncthreads();
    #pragma unroll
    for (int i = 0; i < 2; ++i) {
      const int chunk = i * 4 + w;
      gload_lds16(A + (size_t)(Mt + chunk * 16 + srow) * K + k0 + scol, As + chunk * 512);
    }
    gload_lds16(B + (size_t)(Nt + w * 16 + srow) * K + k0 + scol, Bs + w * 512);
    asm volatile("s_waitcnt vmcnt(0)" ::: "memory");
    __syncthreads();
    s16x8 fa[4], fb[2];
    #pragma unroll
    for (int i = 0; i < 4; ++i)
      fa[i] = *(const s16x8*)(As + (wr + i * 16 + lr) * 32 + lg * 8);
    #pragma unroll
    for (int j = 0; j < 2; ++j)
      fb[j] = *(const s16x8*)(Bs + (wc + j * 16 + lr) * 32 + lg * 8);
    #pragma unroll
    for (int i = 0; i < 4; ++i)
      #pragma unroll
      for (int j = 0; j < 2; ++j)
        acc[i][j] = mfma16(fa[i], fb[j], acc[i][j]);
  }

  #pragma unroll
  for (int i = 0; i < 4; ++i) {
    #pragma unroll
    for (int j = 0; j < 2; ++j) {
      #pragma unroll
      for (int r = 0; r < 4; ++r) {
        const int m = Mt + wr + i * 16 + lg * 4 + r;
        const int n = Nt + wc + j * 16 + lr;
        const size_t idx = (size_t)m * DIM + n;
        outf[idx] = resid[idx] + acc[i][j][r] + bias[n];
      }
    }
  }
}

// ---------------- Kernel A: flash attention, 32 q-rows/wave, shared K/V LDS staging --
__global__ __launch_bounds__(256, 2) void attn_flash(
    const u16* __restrict__ qg, const u16* __restrict__ kg, const u16* __restrict__ vtg,
    float* __restrict__ rinv_out, u16* __restrict__ obf) {
  __shared__ char Ks[2][9216];   // [buf][64 rows x 144B]
  __shared__ char Vs[2][9216];
  __shared__ u16 Pl[4][2048];    // per-wave 4KB P chunk
  const int bid0 = blockIdx.x;
  const int bid = (bid0 & 7) * 64 + (bid0 >> 3);   // XCD-chunked (512 % 8 == 0)
  const int tid = threadIdx.x;
  const int w = tid >> 6, l = tid & 63;
  const int lr = l & 15, lg = l >> 4;
  const int task = bid * 4 + w;     // 64 tasks per bh; all 4 waves same bh
  const int bh = task >> 6;
  const int q0 = (task & 63) << 5;
  const u16* qh = qg + (size_t)bh * 131072;
  const char* kgb = (const char*)(kg + (size_t)bh * 131072);
  const char* vgb = (const char*)(vtg + (size_t)bh * 131072);
  char* myP = (char*)&Pl[w][0];
  const int swz = (lr & 7) << 4;

  const int o0 = tid * 16, o1 = tid * 16 + 4096;
  const int r0 = o0 >> 7, c0 = o0 & 127;
  const int r1 = o1 >> 7, c1 = o1 & 127;

  s16x8 bq[2][2];
  #pragma unroll
  for (int g = 0; g < 2; ++g)
    #pragma unroll
    for (int dh = 0; dh < 2; ++dh)
      bq[g][dh] = *(const s16x8*)(qh + (size_t)(q0 + g * 16 + lr) * 64 + dh * 32 + lg * 8);

  const f32x4 zf = {0.f, 0.f, 0.f, 0.f};
  f32x4 oacc[2][3];
  #pragma unroll
  for (int g = 0; g < 2; ++g)
    #pragma unroll
    for (int d = 0; d < 3; ++d) oacc[g][d] = zf;
  float suml[2] = {0.f, 0.f};

  {
    uint4 k0v = *(const uint4*)(kgb + o0);
    uint4 k1v = *(const uint4*)(kgb + o1);
    uint4 v0v = *(const uint4*)(vgb + (size_t)r0 * 4096 + c0);
    uint4 v1v = *(const uint4*)(vgb + (size_t)r1 * 4096 + c1);
    *(uint4*)(Ks[0] + r0 * 144 + c0) = k0v;
    *(uint4*)(Ks[0] + r1 * 144 + c1) = k1v;
    *(uint4*)(Vs[0] + r0 * 144 + c0) = v0v;
    *(uint4*)(Vs[0] + r1 * 144 + c1) = v1v;
  }

  #pragma unroll 2
  for (int cc = 0; cc < 32; ++cc) {
    const int cur = cc & 1;
    uint4 k0v, k1v, v0v, v1v;
    if (cc < 31) {
      const int cc1 = cc + 1;
      k0v = *(const uint4*)(kgb + cc1 * 8192 + o0);
      k1v = *(const uint4*)(kgb + cc1 * 8192 + o1);
      v0v = *(const uint4*)(vgb + (size_t)r0 * 4096 + cc1 * 128 + c0);
      v1v = *(const uint4*)(vgb + (size_t)r1 * 4096 + cc1 * 128 + c1);
    }
    __syncthreads();

    #pragma unroll
    for (int t = 0; t < 4; ++t) {
      const char* krp = Ks[cur] + (t * 16 + lr) * 144 + lg * 16;
      const s16x8 ak0 = *(const s16x8*)krp;
      const s16x8 ak1 = *(const s16x8*)(krp + 64);
      #pragma unroll
      for (int g = 0; g < 2; ++g) {
        f32x4 c = mfma16(ak0, bq[g][0], zf);
        c = mfma16(ak1, bq[g][1], c);
        f32x4 e;
        #pragma unroll
        for (int r = 0; r < 4; ++r) e[r] = __expf(c[r]);
        suml[g] += (e[0] + e[1]) + (e[2] + e[3]);
        const int q = g * 16 + lr;
        const unsigned int lo = (unsigned int)f2b(e[0]) | ((unsigned int)f2b(e[1]) << 16);
        const unsigned int hi = (unsigned int)f2b(e[2]) | ((unsigned int)f2b(e[3]) << 16);
        *(uint2*)(myP + ((q * 128 + t * 32 + lg * 8) ^ swz)) = make_uint2(lo, hi);
      }
    }
    s16x8 pa[2][2];
    #pragma unroll
    for (int g = 0; g < 2; ++g) {
      const int q = g * 16 + lr;
      #pragma unroll
      for (int ks = 0; ks < 2; ++ks)
        pa[g][ks] = *(const s16x8*)(myP + ((q * 128 + ks * 64 + lg * 16) ^ swz));
    }
    #pragma unroll
    for (int ks = 0; ks < 2; ++ks) {
      #pragma unroll
      for (int d = 0; d < 3; ++d) {
        const s16x8 vb = *(const s16x8*)(Vs[cur] + (d * 16 + lr) * 144 + ks * 64 + lg * 16);
        #pragma unroll
        for (int g = 0; g < 2; ++g)
          oacc[g][d] = mfma16(pa[g][ks], vb, oacc[g][d]);
      }
    }
    if (cc < 31) {
      *(uint4*)(Ks[cur ^ 1] + r0 * 144 + c0) = k0v;
      *(uint4*)(Ks[cur ^ 1] + r1 * 144 + c1) = k1v;
      *(uint4*)(Vs[cur ^ 1] + r0 * 144 + c0) = v0v;
      *(uint4*)(Vs[cur ^ 1] + r1 * 144 + c1) = v1v;
    }
  }

  float rinv[2];
  #pragma unroll
  for (int g = 0; g < 2; ++g) {
    float s = suml[g];
    s += __shfl_xor(s, 16);
    s += __shfl_xor(s, 32);
    rinv[g] = 1.0f / s;
  }
  if (l < 16) {
    rinv_out[bh * 2048 + q0 + l] = rinv[0];
    rinv_out[bh * 2048 + q0 + 16 + l] = rinv[1];
  }
  const int b_ = bh >> 3, h = bh & 7;
  #pragma unroll
  for (int g = 0; g < 2; ++g) {
    #pragma unroll
    for (int r = 0; r < 4; ++r) {
      const float sc = __shfl(rinv[g], lg * 4 + r);
      const int qrow = q0 + g * 16 + lg * 4 + r;
      #pragma unroll
      for (int d = 0; d < 3; ++d) {
        obf[((size_t)b_ * 2048 + qrow) * DIM + h * 48 + d * 16 + lr] = f2b(oacc[g][d][r] * sc);
      }
    }
  }
}

// ---------------- Kernel B: P writer v7 — PLAIN stores, fully sequential block region --
// 1024 blocks x 4 waves; block = (bh, 16-q tile) covering ALL 2048 keys.
// Two 1024-key halves: wave w computes keys [hf*1024+w*256, +256) for all 16 q
// -> LDS [16][1028] -> barrier -> 16 rows x 4KB plain stores in ascending
// address order. Block output region = contiguous 128KB (fill-like pattern).
// XCD swizzle makes bh == XCD id -> K (256KB) stays L2-resident per XCD.
__global__ __launch_bounds__(256, 2) void p_writer(
    const u16* __restrict__ qg, const u16* __restrict__ kg,
    const float* __restrict__ rinv_g, float* __restrict__ pout) {
  __shared__ float Pt[16][1028];   // 65,792 B -> 2 blocks/CU
  const int bid0 = blockIdx.x;
  const int bid = (bid0 & 7) * 128 + (bid0 >> 3);  // 1024 % 8 == 0, bijective
  const int tid = threadIdx.x;
  const int w = tid >> 6, l = tid & 63;
  const int lr = l & 15, lg = l >> 4;
  const int bh = bid >> 7;                 // == bid0 & 7 (per-XCD bh)
  const int q0 = (bid & 127) << 4;
  const u16* qh = qg + (size_t)bh * 131072;
  const u16* kp = kg + (size_t)bh * 131072;

  const s16x8 bq0 = *(const s16x8*)(qh + (size_t)(q0 + lr) * 64 + lg * 8);
  const s16x8 bq1 = *(const s16x8*)(qh + (size_t)(q0 + lr) * 64 + 32 + lg * 8);
  const float rinv = rinv_g[bh * 2048 + q0 + lr];
  const f32x4 zf = {0.f, 0.f, 0.f, 0.f};
  float* pbase = pout + (size_t)bh * 4194304 + (size_t)q0 * 2048;
  const int col = tid * 4;   // 0..1020

  #pragma unroll
  for (int hf = 0; hf < 2; ++hf) {
    const int k0 = (hf << 10) + (w << 8);
    #pragma unroll 4
    for (int kk = 0; kk < 16; ++kk) {
      const u16* kr = kp + (size_t)(k0 + kk * 16 + lr) * 64 + lg * 8;
      const s16x8 ak0 = *(const s16x8*)kr;
      const s16x8 ak1 = *(const s16x8*)(kr + 32);
      f32x4 c = mfma16(ak0, bq0, zf);
      c = mfma16(ak1, bq1, c);
      f32x4 e;
      #pragma unroll
      for (int r = 0; r < 4; ++r) e[r] = __expf(c[r]) * rinv;
      *(f32x4*)&Pt[lr][(w << 8) + kk * 16 + lg * 4] = e;   // q=lr, local key col
    }
    __syncthreads();
    #pragma unroll
    for (int r = 0; r < 16; ++r) {
      const f32x4 vq = *(const f32x4*)&Pt[r][col];
      *(f32x4*)(pbase + (size_t)r * 2048 + (hf << 10) + col) = vq;
    }
    __syncthreads();   // guard LDS reuse for next half
  }
}

// ---------------- launch ----------------
extern "C" void kernel_launch(void* const* d_in, const int* in_sizes, int n_in,
                              void* d_out, int out_size, void* d_ws, size_t ws_size,
                              hipStream_t stream) {
  const float* x    = (const float*)d_in[0];
  const float* wq   = (const float*)d_in[1];
  const float* wk   = (const float*)d_in[2];
  const float* wv   = (const float*)d_in[3];
  const float* wo   = (const float*)d_in[4];
  const float* bo   = (const float*)d_in[5];
  const float* g1   = (const float*)d_in[6];
  const float* b1   = (const float*)d_in[7];
  const float* g2   = (const float*)d_in[8];
  const float* b2   = (const float*)d_in[9];
  const float* wfc1 = (const float*)d_in[10];
  const float* bfc1 = (const float*)d_in[11];
  const float* wfc2 = (const float*)d_in[12];
  const float* bfc2 = (const float*)d_in[13];

  char* ws = (char*)d_ws;
  float* h_y    = (float*)(ws);                 // 12,582,912 B (h, later y in-place)
  u16*  h_bf    = (u16*)(ws + 12582912);        // 6,291,456  (later z_bf)
  u16*  wqkv_b  = (u16*)(ws + 18874368);        // 884,736
  u16*  wo_b    = (u16*)(ws + 19759104);        // 294,912
  u16*  wfc1_b  = (u16*)(ws + 20054016);        // 1,179,648
  u16*  wfc2_b  = (u16*)(ws + 21233664);        // 1,179,648
  u16*  qkv     = (u16*)(ws + 22413312);        // 25,165,824 (q|k|vT, later a_bf)
  u16*  o_bf    = (u16*)(ws + 47579136);        // 6,291,456
  float* rinv_g = (float*)(ws + 53870592);      // 262,144 -> total 54,132,736
  u16*  z_bf    = h_bf;
  u16*  a_bf    = qkv;

  float* y_out    = (float*)d_out;
  float* attn_out = (float*)d_out + 3145728;

  convert_zero<<<2048, 256, 0, stream>>>(wq, wk, wv, wo, wfc1, wfc2,
                                         wqkv_b, wo_b, wfc1_b, wfc2_b, (uint4*)qkv);
  ln_kernel<<<2048, 256, 0, stream>>>(x, g1, b1, h_y, h_bf);
  gemm_nt<0><<<dim3(64, 9), 256, 0, stream>>>(h_bf, wqkv_b, 384, nullptr, nullptr, nullptr, qkv);
  attn_flash<<<512, 256, 0, stream>>>(qkv, qkv + 4194304, qkv + 8388608, rinv_g, o_bf);
  p_writer<<<1024, 256, 0, stream>>>(qkv, qkv + 4194304, rinv_g, attn_out);
  gemm_n64<<<dim3(64, 6), 256, 0, stream>>>(o_bf, wo_b, 384, bo, h_y, h_y);
  ln_kernel<<<2048, 256, 0, stream>>>(h_y, g2, b2, nullptr, z_bf);
  gemm_nt<2><<<dim3(64, 12), 256, 0, stream>>>(z_bf, wfc1_b, 384, bfc1, nullptr, nullptr, a_bf);
  gemm_n64<<<dim3(64, 6), 256, 0, stream>>>(a_bf, wfc2_b, 1536, bfc2, h_y, y_out);
}